// Round 2
// baseline (1677.634 us; speedup 1.0000x reference)
//
#include <hip/hip_runtime.h>
#include <cstdint>

#define BATCH 8
#define NPART 2048
#define DDIM 8
#define JCHUNK 1024
#define NN (NPART * NPART) /* 4194304 pairs per batch */

constexpr float LR = 0.1f;
constexpr float ALPHA = 0.9f;
constexpr float EPS = 1e-8f;
constexpr float INV_N = 1.0f / (float)NPART;

// ---------------------------------------------------------------------------
// Wave-aggregated histogram add: one LDS atomic per DISTINCT bin per wave
// (values are heavily clustered -> ~64x fewer atomics than per-lane adds).
// All 64 lanes participate in the ballots; `active` is wave-uniform.
// ---------------------------------------------------------------------------
__device__ __forceinline__ void wave_hist_add(unsigned* lh, unsigned bin, bool pred) {
    unsigned long long active = __ballot(pred);
    const int lane64 = (int)(threadIdx.x & 63);
    while (active) {
        const int leader = __ffsll(active) - 1;
        const unsigned lb = __shfl(bin, leader, 64);
        const unsigned long long match = __ballot(pred && (bin == lb));
        if (lane64 == leader) atomicAdd(&lh[lb], (unsigned)__popcll(match));
        active &= ~match;
    }
}

// ---------------------------------------------------------------------------
// init: zero RMSprop state s, zero radix histograms, init select states.
// rank is 1-indexed target order statistic among remaining candidates.
// median of even-count array = avg of order stats n/2 and n/2+1 (1-indexed).
// ---------------------------------------------------------------------------
__global__ __launch_bounds__(256) void init_ws_k(float* __restrict__ s,
                                                 unsigned* __restrict__ hist,
                                                 unsigned* __restrict__ prefix,
                                                 unsigned* __restrict__ rank) {
    const int tid = blockIdx.x * 256 + threadIdx.x;
    const int stride = gridDim.x * 256;
    for (int q = tid; q < BATCH * NPART * DDIM; q += stride) s[q] = 0.0f;
    if (tid < BATCH * 2 * 256) hist[tid] = 0u;
    if (tid < BATCH * 2) {
        prefix[tid] = 0u;
        rank[tid] = (unsigned)(NN / 2) + (unsigned)(tid & 1); // 2097152 / 2097153
    }
}

// ---------------------------------------------------------------------------
// radix-select histogram pass: count candidates (pairwise sq dist as uint32
// bit pattern, monotone for non-negative floats) matching each selection's
// current prefix, binned on the current 8-bit digit.
// grid: (BATCH, 64); block: 256 = 32 rows x 8 lanes.
// ---------------------------------------------------------------------------
__global__ __launch_bounds__(256) void median_hist_k(const float* __restrict__ x,
                                                     unsigned* __restrict__ hist,
                                                     const unsigned* __restrict__ prefix,
                                                     int shift) {
    __shared__ __align__(16) float4 xs0[JCHUNK]; // j dims 0-3 (split arrays:
    __shared__ __align__(16) float4 xs1[JCHUNK]; //  8-phase b128 reads, no alias)
    __shared__ unsigned lh[512];                 // 2 x 256 bins

    const int b = blockIdx.x;
    const int tid = threadIdx.x;
    const float* xb = x + (size_t)b * NPART * DDIM;

    lh[tid] = 0u;
    lh[tid + 256] = 0u;

    const unsigned p0 = prefix[2 * b + 0];
    const unsigned p1 = prefix[2 * b + 1];
    const bool same = (p0 == p1); // both medians on the same radix path (common)
    const unsigned mask = (shift == 24) ? 0u : (0xFFFFFFFFu << (shift + 8));

    const int lane = tid & 7;
    const int row = tid >> 3;
    const int i = blockIdx.y * 32 + row;

    const float4 xv0 = ((const float4*)(xb + (size_t)i * DDIM))[0];
    const float4 xv1 = ((const float4*)(xb + (size_t)i * DDIM))[1];
    const float xi0 = xv0.x, xi1 = xv0.y, xi2 = xv0.z, xi3 = xv0.w;
    const float xi4 = xv1.x, xi5 = xv1.y, xi6 = xv1.z, xi7 = xv1.w;

    for (int cbase = 0; cbase < NPART; cbase += JCHUNK) {
        __syncthreads(); // protect xs reuse (and cover lh zeroing first time)
        for (int t = tid; t < JCHUNK * 2; t += 256) {
            const float4 v = ((const float4*)(xb + (size_t)cbase * DDIM))[t];
            float4* dst = (t & 1) ? xs1 : xs0;
            dst[t >> 1] = v;
        }
        __syncthreads();
        for (int j = lane; j < JCHUNK; j += 8) {
            const float4 a = xs0[j];
            const float4 c4 = xs1[j];
            float d, sq = 0.0f;
            d = xi0 - a.x;  sq = fmaf(d, d, sq);
            d = xi1 - a.y;  sq = fmaf(d, d, sq);
            d = xi2 - a.z;  sq = fmaf(d, d, sq);
            d = xi3 - a.w;  sq = fmaf(d, d, sq);
            d = xi4 - c4.x; sq = fmaf(d, d, sq);
            d = xi5 - c4.y; sq = fmaf(d, d, sq);
            d = xi6 - c4.z; sq = fmaf(d, d, sq);
            d = xi7 - c4.w; sq = fmaf(d, d, sq);
            const unsigned u = __float_as_uint(sq);
            const unsigned bin = (u >> shift) & 255u;
            wave_hist_add(lh, bin, (u & mask) == p0);
            if (!same) wave_hist_add(lh + 256, bin, (u & mask) == p1);
        }
    }
    __syncthreads();
    const unsigned v0 = lh[tid];
    const unsigned v1 = same ? v0 : lh[tid + 256];
    if (v0) atomicAdd(&hist[b * 512 + tid], v0);
    if (v1) atomicAdd(&hist[b * 512 + 256 + tid], v1);
}

// ---------------------------------------------------------------------------
// scan: per (batch, sel) find the digit bin containing the target rank,
// update prefix/rank, zero hist for the next round. After the final round
// (shift==0) compute h params: neg_inv_h = -1/h, two_over_h = 2/h where
// h = ((sqrt(v1)+sqrt(v2))/2)^2 / log(N).
// ---------------------------------------------------------------------------
__global__ void median_scan_k(unsigned* __restrict__ hist,
                              unsigned* __restrict__ prefix,
                              unsigned* __restrict__ rank,
                              int shift,
                              float* __restrict__ hpar) {
    __shared__ unsigned selv[16];
    const int t = threadIdx.x;
    if (t < 16) {
        const unsigned r = rank[t];
        const unsigned* hb = hist + t * 256;
        unsigned cum = 0;
        int bin = 0;
        for (; bin < 256; ++bin) {
            const unsigned c = hb[bin];
            if (cum + c >= r) break;
            cum += c;
        }
        if (bin > 255) bin = 255;
        const unsigned np = prefix[t] | ((unsigned)bin << shift);
        prefix[t] = np;
        rank[t] = r - cum;
        selv[t] = np;
    }
    __syncthreads();
    for (int q = t; q < 16 * 256; q += 64) hist[q] = 0u;
    if (shift == 0 && t < BATCH) {
        const float v1 = __uint_as_float(selv[2 * t + 0]);
        const float v2 = __uint_as_float(selv[2 * t + 1]);
        const float med = 0.5f * (sqrtf(v1) + sqrtf(v2));
        const float h = (med * med) / logf((float)NPART);
        hpar[2 * t + 0] = -1.0f / h;
        hpar[2 * t + 1] = 2.0f / h;
    }
}

// ---------------------------------------------------------------------------
// one SVGD + RMSprop step.
// phi_id = (1/N) * ( S0*(obs_d - x_id) + (1 + 2/h) * U_d ),
//   S0 = sum_j K_ij, U_d = sum_j K_ij (x_i - x_j)_d   (exactly the reference
//   terms: sum K g = S0*(obs-x_i) + U;  sum K dist = U).
// grid: (BATCH, 64); block 256 = 32 rows x 8 lanes; lane-partial sums are
// combined through a small LDS array (static indexing only).
// ---------------------------------------------------------------------------
__global__ __launch_bounds__(256) void svgd_step_k(const float* __restrict__ x_in,
                                                   float* __restrict__ x_out,
                                                   float* __restrict__ s,
                                                   const float* __restrict__ hpar,
                                                   const float* __restrict__ obs) {
    __shared__ __align__(16) float4 xs0[JCHUNK];
    __shared__ __align__(16) float4 xs1[JCHUNK];
    __shared__ float part[32][8][9]; // 9 KB partials

    const int b = blockIdx.x;
    const int tid = threadIdx.x;
    const float* xb = x_in + (size_t)b * NPART * DDIM;

    const float nih = hpar[2 * b + 0]; // -1/h
    const float c2 = hpar[2 * b + 1];  //  2/h

    const int lane = tid & 7;
    const int row = tid >> 3;
    const int i = blockIdx.y * 32 + row;

    const float4 xv0 = ((const float4*)(xb + (size_t)i * DDIM))[0];
    const float4 xv1 = ((const float4*)(xb + (size_t)i * DDIM))[1];
    const float xi0 = xv0.x, xi1 = xv0.y, xi2 = xv0.z, xi3 = xv0.w;
    const float xi4 = xv1.x, xi5 = xv1.y, xi6 = xv1.z, xi7 = xv1.w;

    float S0 = 0.0f;
    float U0 = 0, U1 = 0, U2 = 0, U3 = 0, U4 = 0, U5 = 0, U6 = 0, U7 = 0;

    for (int cbase = 0; cbase < NPART; cbase += JCHUNK) {
        __syncthreads();
        for (int t = tid; t < JCHUNK * 2; t += 256) {
            const float4 v = ((const float4*)(xb + (size_t)cbase * DDIM))[t];
            float4* dst = (t & 1) ? xs1 : xs0;
            dst[t >> 1] = v;
        }
        __syncthreads();
        for (int j = lane; j < JCHUNK; j += 8) {
            const float4 a = xs0[j];
            const float4 c4 = xs1[j];
            const float d0 = xi0 - a.x;
            const float d1 = xi1 - a.y;
            const float d2 = xi2 - a.z;
            const float d3 = xi3 - a.w;
            const float d4 = xi4 - c4.x;
            const float d5 = xi5 - c4.y;
            const float d6 = xi6 - c4.z;
            const float d7 = xi7 - c4.w;
            float sq = 0.0f;
            sq = fmaf(d0, d0, sq);
            sq = fmaf(d1, d1, sq);
            sq = fmaf(d2, d2, sq);
            sq = fmaf(d3, d3, sq);
            sq = fmaf(d4, d4, sq);
            sq = fmaf(d5, d5, sq);
            sq = fmaf(d6, d6, sq);
            sq = fmaf(d7, d7, sq);
            const float K = expf(sq * nih); // accurate exp: sign-sensitive dynamics
            S0 += K;
            U0 = fmaf(K, d0, U0);
            U1 = fmaf(K, d1, U1);
            U2 = fmaf(K, d2, U2);
            U3 = fmaf(K, d3, U3);
            U4 = fmaf(K, d4, U4);
            U5 = fmaf(K, d5, U5);
            U6 = fmaf(K, d6, U6);
            U7 = fmaf(K, d7, U7);
        }
    }
    part[row][lane][0] = S0;
    part[row][lane][1] = U0;
    part[row][lane][2] = U1;
    part[row][lane][3] = U2;
    part[row][lane][4] = U3;
    part[row][lane][5] = U4;
    part[row][lane][6] = U5;
    part[row][lane][7] = U6;
    part[row][lane][8] = U7;
    __syncthreads();

    // phase 2: thread (r2, d2) reduces 8 lane-partials and applies the update
    const int d2i = tid & 7;
    const int r2 = tid >> 3;
    const int i2 = blockIdx.y * 32 + r2;
    float S0t = 0.0f, Ut = 0.0f;
#pragma unroll
    for (int l = 0; l < 8; ++l) {
        S0t += part[r2][l][0];
        Ut += part[r2][l][1 + d2i];
    }
    const size_t idx = ((size_t)b * NPART + i2) * DDIM + d2i;
    const float xid = x_in[idx];
    const float obsd = obs[b * DDIM + d2i];
    const float T = fmaf(S0t, obsd - xid, Ut);      // sum_j K*(obs - x_j)
    const float phi = INV_N * fmaf(c2, Ut, T);      // + (2/h) * sum_j K*dist
    float sv = s[idx];
    sv = ALPHA * sv + (1.0f - ALPHA) * phi * phi;
    s[idx] = sv;
    x_out[idx] = xid + LR * phi / (sqrtf(sv) + EPS);
}

// ---------------------------------------------------------------------------
extern "C" void kernel_launch(void* const* d_in, const int* in_sizes, int n_in,
                              void* d_out, int out_size, void* d_ws, size_t ws_size,
                              hipStream_t stream) {
    const float* x0 = (const float*)d_in[0];   // [8,2048,8]
    const float* obs = (const float*)d_in[1];  // [8,8]
    float* out = (float*)d_out;                // [8,2048,8]

    // workspace layout (~1.07 MB)
    float* xa = (float*)d_ws;                          // 524288 B ping-pong x
    float* s = xa + BATCH * NPART * DDIM;              // 524288 B RMSprop state
    unsigned* hist = (unsigned*)(s + BATCH * NPART * DDIM); // 16384 B
    unsigned* prefix = hist + BATCH * 2 * 256;         // 64 B
    unsigned* rank = prefix + BATCH * 2;               // 64 B
    float* hpar = (float*)(rank + BATCH * 2);          // 64 B

    init_ws_k<<<256, 256, 0, stream>>>(s, hist, prefix, rank);

    // exact median via 4-round radix select on float bit patterns
    for (int r = 0; r < 4; ++r) {
        const int shift = 24 - 8 * r;
        median_hist_k<<<dim3(BATCH, 64), 256, 0, stream>>>(x0, hist, prefix, shift);
        median_scan_k<<<1, 64, 0, stream>>>(hist, prefix, rank, shift, hpar);
    }

    // 5 SVGD iterations, ping-ponging between d_out and ws; ends in d_out
    svgd_step_k<<<dim3(BATCH, 64), 256, 0, stream>>>(x0, out, s, hpar, obs);
    svgd_step_k<<<dim3(BATCH, 64), 256, 0, stream>>>(out, xa, s, hpar, obs);
    svgd_step_k<<<dim3(BATCH, 64), 256, 0, stream>>>(xa, out, s, hpar, obs);
    svgd_step_k<<<dim3(BATCH, 64), 256, 0, stream>>>(out, xa, s, hpar, obs);
    svgd_step_k<<<dim3(BATCH, 64), 256, 0, stream>>>(xa, out, s, hpar, obs);
}

// Round 6
// 306.681 us; speedup vs baseline: 5.4703x; 5.4703x over previous
//
#include <hip/hip_runtime.h>
#include <cstdint>

#define BATCH 8
#define NPART 2048
#define DDIM 8
#define NN (NPART * NPART) /* 4194304 pairs per batch */

// median kernel tiling: 16 rows x 16 lanes, JCHUNK=256 (8 KB stage + 32 KB hist)
#define MJCHUNK 256
// svgd kernel tiling: 16 rows x 16 lanes, JCHUNK=512 (16 KB stage)
#define SJCHUNK 512

constexpr float LR = 0.1f;
constexpr float ALPHA = 0.9f;
constexpr float EPS = 1e-8f;
constexpr float INV_N = 1.0f / (float)NPART;

// ---------------------------------------------------------------------------
// init: zero RMSprop state s, zero radix histograms, init select states.
// rank is 1-indexed target order statistic among remaining candidates.
// median of even-count array = avg of order stats n/2 and n/2+1 (1-indexed).
// ---------------------------------------------------------------------------
__global__ __launch_bounds__(256) void init_ws_k(float* __restrict__ s,
                                                 unsigned* __restrict__ hist,
                                                 unsigned* __restrict__ prefix,
                                                 unsigned* __restrict__ rank) {
    const int tid = blockIdx.x * 256 + threadIdx.x;
    const int stride = gridDim.x * 256;
    for (int q = tid; q < BATCH * NPART * DDIM; q += stride) s[q] = 0.0f;
    if (tid < BATCH * 2 * 256) hist[tid] = 0u;
    if (tid < BATCH * 2) {
        prefix[tid] = 0u;
        rank[tid] = (unsigned)(NN / 2) + (unsigned)(tid & 1); // 2097152 / 2097153
    }
}

// ---------------------------------------------------------------------------
// radix-select histogram pass over pairwise sq-distance bit patterns.
// Slot-privatized LDS histogram: lh[bin*32 + (tid&31)] -> bank == slot, so a
// wave's 64 atomics land 2 lanes/bank (free) regardless of bin clustering.
// No cross-lane ops in the hot loop. grid (BATCH, 128); block 256 = 16x16.
// ---------------------------------------------------------------------------
__global__ __launch_bounds__(256) void median_hist_k(const float* __restrict__ x,
                                                     unsigned* __restrict__ hist,
                                                     const unsigned* __restrict__ prefix,
                                                     int shift) {
    __shared__ __align__(16) float4 xs0[MJCHUNK]; // j dims 0-3
    __shared__ __align__(16) float4 xs1[MJCHUNK]; // j dims 4-7
    __shared__ unsigned lh[256 * 32];             // 32 KB slot-privatized bins

    const int b = blockIdx.x;
    const int tid = threadIdx.x;
    const int slot = tid & 31;
    const float* xb = x + (size_t)b * NPART * DDIM;

    const unsigned p0 = prefix[2 * b + 0];
    const unsigned p1 = prefix[2 * b + 1];
    const bool same = (p0 == p1); // both medians on same radix path (typical)
    const unsigned mask = (shift == 24) ? 0u : (0xFFFFFFFFu << (shift + 8));

    const int lane = tid & 15;
    const int row = tid >> 4;
    const int i = blockIdx.y * 16 + row;

    const float4 xv0 = ((const float4*)(xb + (size_t)i * DDIM))[0];
    const float4 xv1 = ((const float4*)(xb + (size_t)i * DDIM))[1];
    const float xi0 = xv0.x, xi1 = xv0.y, xi2 = xv0.z, xi3 = xv0.w;
    const float xi4 = xv1.x, xi5 = xv1.y, xi6 = xv1.z, xi7 = xv1.w;

    const int nsel = same ? 1 : 2;
    for (int sel = 0; sel < nsel; ++sel) {
        const unsigned pref = sel ? p1 : p0;
        __syncthreads(); // previous use of lh/xs done
        for (int t = tid; t < 256 * 32; t += 256) lh[t] = 0u;

        for (int cbase = 0; cbase < NPART; cbase += MJCHUNK) {
            __syncthreads(); // lh zero visible / xs safe to overwrite
            for (int t = tid; t < MJCHUNK * 2; t += 256) {
                const float4 v = ((const float4*)(xb + (size_t)cbase * DDIM))[t];
                float4* dst = (t & 1) ? xs1 : xs0;
                dst[t >> 1] = v;
            }
            __syncthreads();
            for (int j = lane; j < MJCHUNK; j += 16) {
                const float4 a = xs0[j];
                const float4 c4 = xs1[j];
                float d;
                d = xi0 - a.x;  float sA = d * d;
                d = xi1 - a.y;  sA = fmaf(d, d, sA);
                d = xi2 - a.z;  sA = fmaf(d, d, sA);
                d = xi3 - a.w;  sA = fmaf(d, d, sA);
                d = xi4 - c4.x; float sB = d * d;
                d = xi5 - c4.y; sB = fmaf(d, d, sB);
                d = xi6 - c4.z; sB = fmaf(d, d, sB);
                d = xi7 - c4.w; sB = fmaf(d, d, sB);
                const unsigned u = __float_as_uint(sA + sB);
                if ((u & mask) == pref) {
                    const unsigned bin = (u >> shift) & 255u;
                    atomicAdd(&lh[bin * 32 + slot], 1u);
                }
            }
        }
        __syncthreads();
        // flush: thread t owns bin t; staggered slot read (2 lanes/bank, free)
        unsigned tot = 0;
#pragma unroll
        for (int sct = 0; sct < 32; ++sct) tot += lh[tid * 32 + ((sct + tid) & 31)];
        if (tot) {
            atomicAdd(&hist[b * 512 + sel * 256 + tid], tot);
            if (same) atomicAdd(&hist[b * 512 + 256 + tid], tot);
        }
    }
}

// ---------------------------------------------------------------------------
// scan: per (batch, sel) find the digit bin containing the target rank,
// update prefix/rank, zero hist for next round. After the FINAL round
// (shift==8; top 24 bits resolved, rel err < 2^-15) compute h params:
// h = ((sqrt(v1)+sqrt(v2))/2)^2 / log(N);  hpar = {-1/h, 2/h}.
// ---------------------------------------------------------------------------
__global__ void median_scan_k(unsigned* __restrict__ hist,
                              unsigned* __restrict__ prefix,
                              unsigned* __restrict__ rank,
                              int shift,
                              float* __restrict__ hpar) {
    __shared__ unsigned selv[16];
    const int t = threadIdx.x;
    if (t < 16) {
        const unsigned r = rank[t];
        const unsigned* hb = hist + t * 256;
        unsigned cum = 0;
        int bin = 0;
        for (; bin < 256; ++bin) {
            const unsigned c = hb[bin];
            if (cum + c >= r) break;
            cum += c;
        }
        if (bin > 255) bin = 255;
        const unsigned np = prefix[t] | ((unsigned)bin << shift);
        prefix[t] = np;
        rank[t] = r - cum;
        selv[t] = np;
    }
    __syncthreads();
    for (int q = t; q < 16 * 256; q += 64) hist[q] = 0u;
    if (shift == 8 && t < BATCH) {
        const float v1 = __uint_as_float(selv[2 * t + 0]);
        const float v2 = __uint_as_float(selv[2 * t + 1]);
        const float med = 0.5f * (sqrtf(v1) + sqrtf(v2));
        const float h = (med * med) / logf((float)NPART);
        hpar[2 * t + 0] = -1.0f / h;
        hpar[2 * t + 1] = 2.0f / h;
    }
}

// ---------------------------------------------------------------------------
// one SVGD + RMSprop step.
// phi_id = (1/N) * ( S0*(obs_d - x_id) + (1 + 2/h) * U_d ),
//   S0 = sum_j K_ij, U_d = sum_j K_ij (x_i - x_j)_d   (identical to reference
//   terms: sum K g = S0*(obs-x_i) + U;  sum K dist = U).
// grid (BATCH, 128); block 256 = 16 rows x 16 j-lanes (16 waves/CU).
// ---------------------------------------------------------------------------
__global__ __launch_bounds__(256) void svgd_step_k(const float* __restrict__ x_in,
                                                   float* __restrict__ x_out,
                                                   float* __restrict__ s,
                                                   const float* __restrict__ hpar,
                                                   const float* __restrict__ obs) {
    __shared__ __align__(16) float4 xs0[SJCHUNK];
    __shared__ __align__(16) float4 xs1[SJCHUNK];
    __shared__ float part[16][16][9]; // 9 KB lane-partials

    const int b = blockIdx.x;
    const int tid = threadIdx.x;
    const float* xb = x_in + (size_t)b * NPART * DDIM;

    const float nih = hpar[2 * b + 0]; // -1/h
    const float c2 = hpar[2 * b + 1];  //  2/h

    const int lane = tid & 15;
    const int row = tid >> 4;
    const int i = blockIdx.y * 16 + row;

    const float4 xv0 = ((const float4*)(xb + (size_t)i * DDIM))[0];
    const float4 xv1 = ((const float4*)(xb + (size_t)i * DDIM))[1];
    const float xi0 = xv0.x, xi1 = xv0.y, xi2 = xv0.z, xi3 = xv0.w;
    const float xi4 = xv1.x, xi5 = xv1.y, xi6 = xv1.z, xi7 = xv1.w;

    float S0 = 0.0f;
    float U0 = 0, U1 = 0, U2 = 0, U3 = 0, U4 = 0, U5 = 0, U6 = 0, U7 = 0;

    for (int cbase = 0; cbase < NPART; cbase += SJCHUNK) {
        __syncthreads();
        for (int t = tid; t < SJCHUNK * 2; t += 256) {
            const float4 v = ((const float4*)(xb + (size_t)cbase * DDIM))[t];
            float4* dst = (t & 1) ? xs1 : xs0;
            dst[t >> 1] = v;
        }
        __syncthreads();
        for (int j = lane; j < SJCHUNK; j += 16) {
            const float4 a = xs0[j];
            const float4 c4 = xs1[j];
            const float d0 = xi0 - a.x;
            const float d1 = xi1 - a.y;
            const float d2 = xi2 - a.z;
            const float d3 = xi3 - a.w;
            const float d4 = xi4 - c4.x;
            const float d5 = xi5 - c4.y;
            const float d6 = xi6 - c4.z;
            const float d7 = xi7 - c4.w;
            float sA = d0 * d0;                 // two parallel fma chains
            float sB = d4 * d4;
            sA = fmaf(d1, d1, sA);
            sB = fmaf(d5, d5, sB);
            sA = fmaf(d2, d2, sA);
            sB = fmaf(d6, d6, sB);
            sA = fmaf(d3, d3, sA);
            sB = fmaf(d7, d7, sB);
            const float K = __expf((sA + sB) * nih); // hw exp2; ~1e-5 rel err
            S0 += K;
            U0 = fmaf(K, d0, U0);
            U1 = fmaf(K, d1, U1);
            U2 = fmaf(K, d2, U2);
            U3 = fmaf(K, d3, U3);
            U4 = fmaf(K, d4, U4);
            U5 = fmaf(K, d5, U5);
            U6 = fmaf(K, d6, U6);
            U7 = fmaf(K, d7, U7);
        }
    }
    part[row][lane][0] = S0;
    part[row][lane][1] = U0;
    part[row][lane][2] = U1;
    part[row][lane][3] = U2;
    part[row][lane][4] = U3;
    part[row][lane][5] = U4;
    part[row][lane][6] = U5;
    part[row][lane][7] = U6;
    part[row][lane][8] = U7;
    __syncthreads();

    // phase 2: threads 0..127 -> (row r2, dim d2); reduce 16 lane-partials
    if (tid < 128) {
        const int d2i = tid & 7;
        const int r2 = tid >> 3;
        const int i2 = blockIdx.y * 16 + r2;
        float S0t = 0.0f, Ut = 0.0f;
#pragma unroll
        for (int l = 0; l < 16; ++l) {
            S0t += part[r2][l][0];
            Ut += part[r2][l][1 + d2i];
        }
        const size_t idx = ((size_t)b * NPART + i2) * DDIM + d2i;
        const float xid = x_in[idx];
        const float obsd = obs[b * DDIM + d2i];
        const float T = fmaf(S0t, obsd - xid, Ut); // sum_j K*(obs - x_j)
        const float phi = INV_N * fmaf(c2, Ut, T); // + (2/h) * sum_j K*dist
        float sv = s[idx];
        sv = ALPHA * sv + (1.0f - ALPHA) * phi * phi;
        s[idx] = sv;
        x_out[idx] = xid + LR * phi / (sqrtf(sv) + EPS);
    }
}

// ---------------------------------------------------------------------------
extern "C" void kernel_launch(void* const* d_in, const int* in_sizes, int n_in,
                              void* d_out, int out_size, void* d_ws, size_t ws_size,
                              hipStream_t stream) {
    const float* x0 = (const float*)d_in[0];   // [8,2048,8]
    const float* obs = (const float*)d_in[1];  // [8,8]
    float* out = (float*)d_out;                // [8,2048,8]

    // workspace layout (~1.07 MB)
    float* xa = (float*)d_ws;                          // 524288 B ping-pong x
    float* s = xa + BATCH * NPART * DDIM;              // 524288 B RMSprop state
    unsigned* hist = (unsigned*)(s + BATCH * NPART * DDIM); // 16384 B
    unsigned* prefix = hist + BATCH * 2 * 256;         // 64 B
    unsigned* rank = prefix + BATCH * 2;               // 64 B
    float* hpar = (float*)(rank + BATCH * 2);          // 64 B

    init_ws_k<<<256, 256, 0, stream>>>(s, hist, prefix, rank);

    // median via 3-round radix select on float bit patterns (24 bits: exact
    // to rel err < 2^-15, far below fp32 trajectory noise)
    for (int r = 0; r < 3; ++r) {
        const int shift = 24 - 8 * r;
        median_hist_k<<<dim3(BATCH, 128), 256, 0, stream>>>(x0, hist, prefix, shift);
        median_scan_k<<<1, 64, 0, stream>>>(hist, prefix, rank, shift, hpar);
    }

    // 5 SVGD iterations, ping-ponging between d_out and ws; ends in d_out
    svgd_step_k<<<dim3(BATCH, 128), 256, 0, stream>>>(x0, out, s, hpar, obs);
    svgd_step_k<<<dim3(BATCH, 128), 256, 0, stream>>>(out, xa, s, hpar, obs);
    svgd_step_k<<<dim3(BATCH, 128), 256, 0, stream>>>(xa, out, s, hpar, obs);
    svgd_step_k<<<dim3(BATCH, 128), 256, 0, stream>>>(out, xa, s, hpar, obs);
    svgd_step_k<<<dim3(BATCH, 128), 256, 0, stream>>>(xa, out, s, hpar, obs);
}

// Round 7
// 229.980 us; speedup vs baseline: 7.2947x; 1.3335x over previous
//
#include <hip/hip_runtime.h>
#include <cstdint>

#define BATCH 8
#define NPART 2048
#define DDIM 8
#define NN (NPART * NPART) /* 4194304 pairs per batch */

#define MJCHUNK 256   // median tile: 9 KB stage + 32 KB hist
#define SJCHUNK 512   // svgd tile: 18 KB stage

constexpr float LR = 0.1f;
constexpr float ALPHA = 0.9f;
constexpr float EPS = 1e-8f;
constexpr float INV_N = 1.0f / (float)NPART;

typedef float v2f __attribute__((ext_vector_type(2)));
typedef float v4f __attribute__((ext_vector_type(4)));

// ---------------------------------------------------------------------------
// init: zero RMSprop state s, zero radix histograms, init select states.
// ---------------------------------------------------------------------------
__global__ __launch_bounds__(256) void init_ws_k(float* __restrict__ s,
                                                 unsigned* __restrict__ hist,
                                                 unsigned* __restrict__ prefix,
                                                 unsigned* __restrict__ rank) {
    const int tid = blockIdx.x * 256 + threadIdx.x;
    const int stride = gridDim.x * 256;
    for (int q = tid; q < BATCH * NPART * DDIM; q += stride) s[q] = 0.0f;
    if (tid < BATCH * 2 * 256) hist[tid] = 0u;
    if (tid < BATCH * 2) {
        prefix[tid] = 0u;
        rank[tid] = (unsigned)(NN / 2) + (unsigned)(tid & 1); // 2097152 / 2097153
    }
}

// ---------------------------------------------------------------------------
// radix-select histogram pass. sq = max(|xi|^2+|xj|^2-2<xi,xj>, 0) via packed
// fma dot; slot-privatized LDS histogram (bank == tid&31, 2 lanes/bank, free).
// 2 i-rows per thread. grid (BATCH, 64); block 256 = 16 lanes x 16 trows.
// ---------------------------------------------------------------------------
__global__ __launch_bounds__(256) void median_hist_k(const float* __restrict__ x,
                                                     unsigned* __restrict__ hist,
                                                     const unsigned* __restrict__ prefix,
                                                     int shift) {
    __shared__ __align__(16) v4f xs0[MJCHUNK]; // xj dims 0-3
    __shared__ __align__(16) v4f xs1[MJCHUNK]; // xj dims 4-7
    __shared__ float rs[MJCHUNK];              // |xj|^2
    __shared__ unsigned lh[256 * 32];          // 32 KB slot-privatized bins

    const int b = blockIdx.x;
    const int tid = threadIdx.x;
    const int slot = tid & 31;
    const float* xb = x + (size_t)b * NPART * DDIM;

    const unsigned p0 = prefix[2 * b + 0];
    const unsigned p1 = prefix[2 * b + 1];
    const bool same = (p0 == p1);
    const unsigned mask = (shift == 24) ? 0u : (0xFFFFFFFFu << (shift + 8));

    const int lane = tid & 15;
    const int trow = tid >> 4;
    const int ia = blockIdx.y * 32 + trow;  // row A
    const int ib = ia + 16;                 // row B

    const v4f a0 = ((const v4f*)(xb + (size_t)ia * DDIM))[0];
    const v4f a1 = ((const v4f*)(xb + (size_t)ia * DDIM))[1];
    const v4f b0 = ((const v4f*)(xb + (size_t)ib * DDIM))[0];
    const v4f b1 = ((const v4f*)(xb + (size_t)ib * DDIM))[1];
    float qa = a0.x * a0.x + a0.y * a0.y + a0.z * a0.z + a0.w * a0.w
             + a1.x * a1.x + a1.y * a1.y + a1.z * a1.z + a1.w * a1.w;
    float qb = b0.x * b0.x + b0.y * b0.y + b0.z * b0.z + b0.w * b0.w
             + b1.x * b1.x + b1.y * b1.y + b1.z * b1.z + b1.w * b1.w;

    const int nsel = same ? 1 : 2;
    for (int sel = 0; sel < nsel; ++sel) {
        const unsigned pref = sel ? p1 : p0;
        __syncthreads();
        for (int t = tid; t < 256 * 32; t += 256) lh[t] = 0u;

        for (int cbase = 0; cbase < NPART; cbase += MJCHUNK) {
            __syncthreads();
            for (int t = tid; t < MJCHUNK; t += 256) {
                const v4f u0 = ((const v4f*)(xb + (size_t)(cbase + t) * DDIM))[0];
                const v4f u1 = ((const v4f*)(xb + (size_t)(cbase + t) * DDIM))[1];
                xs0[t] = u0;
                xs1[t] = u1;
                rs[t] = u0.x * u0.x + u0.y * u0.y + u0.z * u0.z + u0.w * u0.w
                      + u1.x * u1.x + u1.y * u1.y + u1.z * u1.z + u1.w * u1.w;
            }
            __syncthreads();
#pragma unroll 4
            for (int j = lane; j < MJCHUNK; j += 16) {
                const v4f A = xs0[j];
                const v4f B = xs1[j];
                const float r = rs[j];
                const v2f A0 = A.xy, A1 = A.zw, B0 = B.xy, B1 = B.zw;
                // row A
                v2f p = A0 * a0.xy;
                p += A1 * a0.zw;
                p += B0 * a1.xy;
                p += B1 * a1.zw;
                float sq = fmaxf(fmaf(-2.0f, p.x + p.y, qa + r), 0.0f);
                unsigned u = __float_as_uint(sq);
                if ((u & mask) == pref)
                    atomicAdd(&lh[((u >> shift) & 255u) * 32 + slot], 1u);
                // row B
                v2f q = A0 * b0.xy;
                q += A1 * b0.zw;
                q += B0 * b1.xy;
                q += B1 * b1.zw;
                sq = fmaxf(fmaf(-2.0f, q.x + q.y, qb + r), 0.0f);
                u = __float_as_uint(sq);
                if ((u & mask) == pref)
                    atomicAdd(&lh[((u >> shift) & 255u) * 32 + slot], 1u);
            }
        }
        __syncthreads();
        unsigned tot = 0;
#pragma unroll
        for (int sct = 0; sct < 32; ++sct) tot += lh[tid * 32 + ((sct + tid) & 31)];
        if (tot) {
            atomicAdd(&hist[b * 512 + sel * 256 + tid], tot);
            if (same) atomicAdd(&hist[b * 512 + 256 + tid], tot);
        }
    }
}

// ---------------------------------------------------------------------------
// scan: find digit bin containing target rank; update prefix/rank; zero hist.
// Final round (shift==8): hpar = {-1/h, 2/h}, h = ((sqrt(v1)+sqrt(v2))/2)^2/logN.
// ---------------------------------------------------------------------------
__global__ void median_scan_k(unsigned* __restrict__ hist,
                              unsigned* __restrict__ prefix,
                              unsigned* __restrict__ rank,
                              int shift,
                              float* __restrict__ hpar) {
    __shared__ unsigned selv[16];
    const int t = threadIdx.x;
    if (t < 16) {
        const unsigned r = rank[t];
        const unsigned* hb = hist + t * 256;
        unsigned cum = 0;
        int bin = 0;
        for (; bin < 256; ++bin) {
            const unsigned c = hb[bin];
            if (cum + c >= r) break;
            cum += c;
        }
        if (bin > 255) bin = 255;
        const unsigned np = prefix[t] | ((unsigned)bin << shift);
        prefix[t] = np;
        rank[t] = r - cum;
        selv[t] = np;
    }
    __syncthreads();
    for (int q = t; q < 16 * 256; q += 64) hist[q] = 0u;
    if (shift == 8 && t < BATCH) {
        const float v1 = __uint_as_float(selv[2 * t + 0]);
        const float v2 = __uint_as_float(selv[2 * t + 1]);
        const float med = 0.5f * (sqrtf(v1) + sqrtf(v2));
        const float h = (med * med) / logf((float)NPART);
        hpar[2 * t + 0] = -1.0f / h;
        hpar[2 * t + 1] = 2.0f / h;
    }
}

// ---------------------------------------------------------------------------
// one SVGD + RMSprop step, dot-expansion form:
//   K = exp(nih*(|xi|^2 + |xj|^2 - 2<xi,xj>)),  nih = -1/h
//   S0 = sum_j K;  V_d = sum_j K*xj_d;  U_d = S0*xi_d - V_d
//   phi = (1/N) * ( S0*(obs_d - xi_d) + (1 + 2/h)*U_d )
// 2 i-rows/thread, packed-float2 fma chains. grid (BATCH, 64); block 256.
// ---------------------------------------------------------------------------
__global__ __launch_bounds__(256) void svgd_step_k(const float* __restrict__ x_in,
                                                   float* __restrict__ x_out,
                                                   float* __restrict__ s,
                                                   const float* __restrict__ hpar,
                                                   const float* __restrict__ obs) {
    __shared__ __align__(16) v4f xs0[SJCHUNK];
    __shared__ __align__(16) v4f xs1[SJCHUNK];
    __shared__ float rs[SJCHUNK];        // nih*|xj|^2
    __shared__ float part[32][16][9];    // 18 KB partials

    const int b = blockIdx.x;
    const int tid = threadIdx.x;
    const float* xb = x_in + (size_t)b * NPART * DDIM;

    const float nih = hpar[2 * b + 0];   // -1/h
    const float c2 = hpar[2 * b + 1];    //  2/h
    const float cdot = -2.0f * nih;

    const int lane = tid & 15;
    const int trow = tid >> 4;
    const int ia = blockIdx.y * 32 + trow;
    const int ib = ia + 16;

    const v4f a0 = ((const v4f*)(xb + (size_t)ia * DDIM))[0];
    const v4f a1 = ((const v4f*)(xb + (size_t)ia * DDIM))[1];
    const v4f b0 = ((const v4f*)(xb + (size_t)ib * DDIM))[0];
    const v4f b1 = ((const v4f*)(xb + (size_t)ib * DDIM))[1];
    const float qa = nih * (a0.x * a0.x + a0.y * a0.y + a0.z * a0.z + a0.w * a0.w
                          + a1.x * a1.x + a1.y * a1.y + a1.z * a1.z + a1.w * a1.w);
    const float qb = nih * (b0.x * b0.x + b0.y * b0.y + b0.z * b0.z + b0.w * b0.w
                          + b1.x * b1.x + b1.y * b1.y + b1.z * b1.z + b1.w * b1.w);

    float S0a = 0.0f, S0b = 0.0f;
    v2f Va0 = {0, 0}, Va1 = {0, 0}, Va2 = {0, 0}, Va3 = {0, 0};
    v2f Vb0 = {0, 0}, Vb1 = {0, 0}, Vb2 = {0, 0}, Vb3 = {0, 0};

    for (int cbase = 0; cbase < NPART; cbase += SJCHUNK) {
        __syncthreads();
        for (int t = tid; t < SJCHUNK; t += 256) {
            const v4f u0 = ((const v4f*)(xb + (size_t)(cbase + t) * DDIM))[0];
            const v4f u1 = ((const v4f*)(xb + (size_t)(cbase + t) * DDIM))[1];
            xs0[t] = u0;
            xs1[t] = u1;
            rs[t] = nih * (u0.x * u0.x + u0.y * u0.y + u0.z * u0.z + u0.w * u0.w
                         + u1.x * u1.x + u1.y * u1.y + u1.z * u1.z + u1.w * u1.w);
        }
        __syncthreads();
#pragma unroll 4
        for (int j = lane; j < SJCHUNK; j += 16) {
            const v4f A = xs0[j];
            const v4f B = xs1[j];
            const float r = rs[j];
            const v2f A0 = A.xy, A1 = A.zw, B0 = B.xy, B1 = B.zw;
            // row A
            v2f p = A0 * a0.xy;
            p += A1 * a0.zw;
            p += B0 * a1.xy;
            p += B1 * a1.zw;
            const float Ka = __expf(fmaf(cdot, p.x + p.y, qa + r));
            S0a += Ka;
            const v2f Ka2 = {Ka, Ka};
            Va0 += A0 * Ka2;
            Va1 += A1 * Ka2;
            Va2 += B0 * Ka2;
            Va3 += B1 * Ka2;
            // row B
            v2f q = A0 * b0.xy;
            q += A1 * b0.zw;
            q += B0 * b1.xy;
            q += B1 * b1.zw;
            const float Kb = __expf(fmaf(cdot, q.x + q.y, qb + r));
            S0b += Kb;
            const v2f Kb2 = {Kb, Kb};
            Vb0 += A0 * Kb2;
            Vb1 += A1 * Kb2;
            Vb2 += B0 * Kb2;
            Vb3 += B1 * Kb2;
        }
    }
    part[trow][lane][0] = S0a;
    part[trow][lane][1] = Va0.x;
    part[trow][lane][2] = Va0.y;
    part[trow][lane][3] = Va1.x;
    part[trow][lane][4] = Va1.y;
    part[trow][lane][5] = Va2.x;
    part[trow][lane][6] = Va2.y;
    part[trow][lane][7] = Va3.x;
    part[trow][lane][8] = Va3.y;
    part[trow + 16][lane][0] = S0b;
    part[trow + 16][lane][1] = Vb0.x;
    part[trow + 16][lane][2] = Vb0.y;
    part[trow + 16][lane][3] = Vb1.x;
    part[trow + 16][lane][4] = Vb1.y;
    part[trow + 16][lane][5] = Vb2.x;
    part[trow + 16][lane][6] = Vb2.y;
    part[trow + 16][lane][7] = Vb3.x;
    part[trow + 16][lane][8] = Vb3.y;
    __syncthreads();

    // phase 2: 256 threads = 32 rows x 8 dims; reduce 16 lane-partials
    {
        const int d2i = tid & 7;
        const int r2 = tid >> 3;
        const int i2 = blockIdx.y * 32 + r2;
        float S0t = 0.0f, Vt = 0.0f;
#pragma unroll
        for (int l = 0; l < 16; ++l) {
            S0t += part[r2][l][0];
            Vt += part[r2][l][1 + d2i];
        }
        const size_t idx = ((size_t)b * NPART + i2) * DDIM + d2i;
        const float xid = x_in[idx];
        const float obsd = obs[b * DDIM + d2i];
        const float U = fmaf(S0t, xid, -Vt);       // sum_j K*(xi - xj)
        const float T = fmaf(S0t, obsd - xid, U);  // sum_j K*(obs - xj)
        const float phi = INV_N * fmaf(c2, U, T);
        float sv = s[idx];
        sv = ALPHA * sv + (1.0f - ALPHA) * phi * phi;
        s[idx] = sv;
        x_out[idx] = xid + LR * phi / (sqrtf(sv) + EPS);
    }
}

// ---------------------------------------------------------------------------
extern "C" void kernel_launch(void* const* d_in, const int* in_sizes, int n_in,
                              void* d_out, int out_size, void* d_ws, size_t ws_size,
                              hipStream_t stream) {
    const float* x0 = (const float*)d_in[0];   // [8,2048,8]
    const float* obs = (const float*)d_in[1];  // [8,8]
    float* out = (float*)d_out;                // [8,2048,8]

    // workspace layout (~1.07 MB)
    float* xa = (float*)d_ws;                          // ping-pong x
    float* s = xa + BATCH * NPART * DDIM;              // RMSprop state
    unsigned* hist = (unsigned*)(s + BATCH * NPART * DDIM);
    unsigned* prefix = hist + BATCH * 2 * 256;
    unsigned* rank = prefix + BATCH * 2;
    float* hpar = (float*)(rank + BATCH * 2);

    init_ws_k<<<256, 256, 0, stream>>>(s, hist, prefix, rank);

    // median via 3-round radix select on float bit patterns (top 24 bits)
    for (int r = 0; r < 3; ++r) {
        const int shift = 24 - 8 * r;
        median_hist_k<<<dim3(BATCH, 64), 256, 0, stream>>>(x0, hist, prefix, shift);
        median_scan_k<<<1, 64, 0, stream>>>(hist, prefix, rank, shift, hpar);
    }

    // 5 SVGD iterations, ping-ponging between d_out and ws; ends in d_out
    svgd_step_k<<<dim3(BATCH, 64), 256, 0, stream>>>(x0, out, s, hpar, obs);
    svgd_step_k<<<dim3(BATCH, 64), 256, 0, stream>>>(out, xa, s, hpar, obs);
    svgd_step_k<<<dim3(BATCH, 64), 256, 0, stream>>>(xa, out, s, hpar, obs);
    svgd_step_k<<<dim3(BATCH, 64), 256, 0, stream>>>(out, xa, s, hpar, obs);
    svgd_step_k<<<dim3(BATCH, 64), 256, 0, stream>>>(xa, out, s, hpar, obs);
}